// Round 4
// baseline (161.003 us; speedup 1.0000x reference)
//
#include <hip/hip_runtime.h>
#include <stdint.h>

// ---------------- common types/helpers ----------------
typedef __attribute__((ext_vector_type(4))) float f32x4;
typedef _Float16 half8 __attribute__((ext_vector_type(8)));
typedef _Float16 half2v __attribute__((ext_vector_type(2)));

#define LDK 200  // LDS row pitch (halves): 192+8, rows 400B (16B-aligned)
#define QSCALE 0.17677669529663689f  // 32^-0.5

__device__ __forceinline__ float dot2f(unsigned int k2, unsigned int q2, float c) {
#if __has_builtin(__builtin_amdgcn_fdot2)
  return __builtin_amdgcn_fdot2(__builtin_bit_cast(half2v, k2),
                                __builtin_bit_cast(half2v, q2), c, false);
#else
  half2v a = __builtin_bit_cast(half2v, k2), b = __builtin_bit_cast(half2v, q2);
  return c + (float)a.x * (float)b.x + (float)a.y * (float)b.y;
#endif
}

// ---------------- kernel 0: prep (weights -> f16; q-scale folded; scaled bias) ----------------
__global__ __launch_bounds__(256) void prep_w(
    const float* __restrict__ qw, const float* __restrict__ qb,
    const float* __restrict__ pw,
    _Float16* __restrict__ qwh, float* __restrict__ qbs, _Float16* __restrict__ pwh) {
  int i = blockIdx.x * 256 + threadIdx.x;
  if (i < 27648) {  // qkv_w: 110592/4 float4s; 48 per row (no straddle)
    float4 v = ((const float4*)qw)[i];
    int n = (i * 4) / 192;
    float sc = ((n % 192) < 64) ? QSCALE : 1.0f;
    _Float16* d = qwh + i * 4;
    d[0] = (_Float16)(v.x * sc); d[1] = (_Float16)(v.y * sc);
    d[2] = (_Float16)(v.z * sc); d[3] = (_Float16)(v.w * sc);
  } else if (i < 36864) {  // proj_w: 9216 float4s
    int k = i - 27648;
    float4 v = ((const float4*)pw)[k];
    _Float16* d = pwh + k * 4;
    d[0] = (_Float16)v.x; d[1] = (_Float16)v.y;
    d[2] = (_Float16)v.z; d[3] = (_Float16)v.w;
  } else if (i < 36864 + 576) {
    int n = i - 36864;
    qbs[n] = qb[n] * (((n % 192) < 64) ? QSCALE : 1.0f);
  }
}

// ---------------- kernel 1: qkv GEMM ----------------
// qkv[pixel][576] = x^T @ qkv_w^T + b (f16 out, q pre-scaled).
// Grid (512 px-tiles, 3 qkv-thirds): A staged per block; B direct from global (L2-hot).
__global__ __launch_bounds__(256) void qkv_gemm(
    const float* __restrict__ x, const _Float16* __restrict__ wh,
    const float* __restrict__ qbs, _Float16* __restrict__ qkv) {
  __shared__ _Float16 Al[64 * LDK];
  const int t = threadIdx.x;
  const int tm = blockIdx.x;  // 512 pixel tiles
  const int ng = blockIdx.y;  // qkv third: n in [ng*192, ng*192+192)
  const int bb = (tm * 64) >> 12, hw0 = (tm * 64) & 4095;
  const float* xb = x + (size_t)bb * 192 * 4096 + hw0;

  // stage A: 64 px x 192 ch, transpose from NCHW; float4 loads (coalesced)
  #pragma unroll
  for (int j = 0; j < 12; ++j) {
    int idx = j * 256 + t;
    int m4 = (idx & 15) * 4, c = idx >> 4;
    float4 v = *(const float4*)(xb + (size_t)c * 4096 + m4);
    Al[(m4 + 0) * LDK + c] = (_Float16)v.x;
    Al[(m4 + 1) * LDK + c] = (_Float16)v.y;
    Al[(m4 + 2) * LDK + c] = (_Float16)v.z;
    Al[(m4 + 3) * LDK + c] = (_Float16)v.w;
  }
  __syncthreads();

  const int lane = t & 63, wid = t >> 6;
  const int wm = (wid >> 1) * 32, wn = (wid & 1) * 32;  // 2x2 waves, 32x32 each
  const int lr = lane & 15, kb = (lane >> 4) * 8;
  const int r0 = (lane >> 4) * 4;
  _Float16* opb = qkv + (size_t)(tm * 64) * 576;

  for (int n0 = ng * 192; n0 < ng * 192 + 192; n0 += 64) {
    f32x4 acc[2][2];
    #pragma unroll
    for (int i = 0; i < 2; ++i)
      #pragma unroll
      for (int j = 0; j < 2; ++j)
        #pragma unroll
        for (int r = 0; r < 4; ++r) acc[i][j][r] = 0.0f;

    #pragma unroll
    for (int kk = 0; kk < 192; kk += 32) {
      half8 a0 = *(const half8*)&Al[(wm + lr) * LDK + kk + kb];
      half8 a1 = *(const half8*)&Al[(wm + 16 + lr) * LDK + kk + kb];
      half8 b0 = *(const half8*)(wh + (size_t)(n0 + wn + lr) * 192 + kk + kb);
      half8 b1 = *(const half8*)(wh + (size_t)(n0 + wn + 16 + lr) * 192 + kk + kb);
      acc[0][0] = __builtin_amdgcn_mfma_f32_16x16x32_f16(a0, b0, acc[0][0], 0, 0, 0);
      acc[0][1] = __builtin_amdgcn_mfma_f32_16x16x32_f16(a0, b1, acc[0][1], 0, 0, 0);
      acc[1][0] = __builtin_amdgcn_mfma_f32_16x16x32_f16(a1, b0, acc[1][0], 0, 0, 0);
      acc[1][1] = __builtin_amdgcn_mfma_f32_16x16x32_f16(a1, b1, acc[1][1], 0, 0, 0);
    }

    // D: col (= weight n) = lane&15, row (= pixel) = (lane>>4)*4 + reg
    #pragma unroll
    for (int i = 0; i < 2; ++i)
      #pragma unroll
      for (int j = 0; j < 2; ++j) {
        int gn = n0 + wn + j * 16 + lr;
        float bs = qbs[gn];
        #pragma unroll
        for (int r = 0; r < 4; ++r) {
          int row = wm + i * 16 + r0 + r;
          opb[row * 576 + gn] = (_Float16)(acc[i][j][r] + bs);
        }
      }
  }
}

// ---------------- kernel 2: neighborhood attention (class-tiled, LDS halo) ----------------
template <int K, int DIL>
__device__ __forceinline__ void natten_branch(
    const _Float16* __restrict__ qkv, const float* __restrict__ rpb,
    _Float16* __restrict__ yo, const int branch, const int r,
    unsigned short* __restrict__ smem) {
  constexpr int RW = 2 * K - 1;
  constexpr int H8 = K + 7;        // halo span = 8 + K - 1
  constexpr int NH = H8 * H8;
  constexpr int NL = (K * K + 3) / 4;
  constexpr int LSTR = 40;         // halves per halo row (32 + 8 pad), 80B

  _Float16* Kl = (_Float16*)smem;
  _Float16* Vl = Kl + NH * LSTR;
  _Float16* Ql = Vl + NH * LSTR;
  float* rs = (float*)(Ql + 64 * LSTR);

  const int t = threadIdx.x;
  const int bh = r & 15;
  const int head = bh & 1, bb = bh >> 1;
  const int rr = r >> 4;
  int gh, gw, ti, tj, Lgh, Lgw;
  if (DIL == 1) {
    gh = 0; gw = 0; ti = (rr >> 3) * 8; tj = (rr & 7) * 8; Lgh = 64; Lgw = 64;
  } else if (DIL == 2) {
    int cls = rr >> 4, tile = rr & 15;
    gh = cls >> 1; gw = cls & 1; ti = (tile >> 2) * 8; tj = (tile & 3) * 8;
    Lgh = 32; Lgw = 32;
  } else {
    int cls = rr / 9, tile = rr % 9;
    gh = cls / 3; gw = cls % 3; ti = (tile / 3) * 8; tj = (tile % 3) * 8;
    Lgh = (64 - gh + 2) / 3; Lgw = (64 - gw + 2) / 3;
  }
  const int hoh = max(0, min(ti - K / 2, Lgh - K));
  const int how = max(0, min(tj - K / 2, Lgw - K));

  for (int i = t; i < RW * RW; i += 256) rs[i] = rpb[head * RW * RW + i];

  // stage halo K/V (each 16B chunk by one thread)
  const _Float16* kvb = qkv + (size_t)bb * 4096 * 576 + branch * 192 + 64 + head * 32;
  for (int L = t; L < NH * 8; L += 256) {
    int px = L >> 3, part = L & 7;
    int hr = px / H8, hc = px % H8;
    int cr = min(hoh + hr, Lgh - 1), cc = min(how + hc, Lgw - 1);
    int ph = gh + cr * DIL, pw2 = gw + cc * DIL;
    const _Float16* src = kvb + (size_t)(ph * 64 + pw2) * 576 + (part & 3) * 8 + ((part & 4) ? 64 : 0);
    _Float16* dst = ((part & 4) ? Vl : Kl) + px * LSTR + (part & 3) * 8;
    *(uint4*)dst = *(const uint4*)src;
  }
  // stage Q for 64 tile queries (clamped for ragged edges)
  {
    int qi = t >> 2, part = t & 3;
    int ci0 = min(ti + (qi >> 3), Lgh - 1), cj0 = min(tj + (qi & 7), Lgw - 1);
    int ph = gh + ci0 * DIL, pw2 = gw + cj0 * DIL;
    const _Float16* src = qkv + (size_t)((size_t)bb * 4096 + ph * 64 + pw2) * 576
                          + branch * 192 + head * 32 + part * 8;
    *(uint4*)(Ql + qi * LSTR + part * 8) = *(const uint4*)src;
  }
  __syncthreads();

  const int qi = t >> 2, sl = t & 3;
  const int ci = ti + (qi >> 3), cj = tj + (qi & 7);
  const bool valid = (ci < Lgh) && (cj < Lgw);

  int s0h = ci - K / 2; if (s0h < 0) s0h = 0; if (s0h > Lgh - K) s0h = Lgh - K;
  int s0w = cj - K / 2; if (s0w < 0) s0w = 0; if (s0w > Lgw - K) s0w = Lgw - K;
  const int rbase = s0h - hoh, cbase = s0w - how;          // in [0,7]
  const int bhb = s0h - ci + K - 1, bwb = s0w - cj + K - 1;

  // q packed pairs from LDS (broadcast within 4-lane group)
  unsigned int qh[16];
  #pragma unroll
  for (int u = 0; u < 4; ++u) {
    uint4 v = *(const uint4*)(Ql + qi * LSTR + u * 8);
    qh[u * 4 + 0] = v.x; qh[u * 4 + 1] = v.y; qh[u * 4 + 2] = v.z; qh[u * 4 + 3] = v.w;
  }

  // pass 1: scores for this lane's neighbors (n = sl + 4j)
  float s[NL];
  float mx = -1e30f;
  #pragma unroll
  for (int j = 0; j < NL; ++j) {
    int n = sl + 4 * j;
    if (n < K * K) {
      int kh = n / K, kw = n % K;
      int lidx = (rbase + kh) * H8 + (cbase + kw);
      const _Float16* kp = Kl + lidx * LSTR;
      float sc = rs[(bhb + kh) * RW + (bwb + kw)];
      #pragma unroll
      for (int u = 0; u < 4; ++u) {
        uint4 kv = *(const uint4*)(kp + u * 8);
        sc = dot2f(kv.x, qh[4 * u + 0], sc);
        sc = dot2f(kv.y, qh[4 * u + 1], sc);
        sc = dot2f(kv.z, qh[4 * u + 2], sc);
        sc = dot2f(kv.w, qh[4 * u + 3], sc);
      }
      s[j] = sc;
      mx = fmaxf(mx, sc);
    } else {
      s[j] = -1e30f;
    }
  }
  // merge max over the 4 lanes of this query
  mx = fmaxf(mx, __shfl_xor(mx, 1, 64));
  mx = fmaxf(mx, __shfl_xor(mx, 2, 64));

  float pw[NL];
  float l = 0.0f;
  #pragma unroll
  for (int j = 0; j < NL; ++j) { pw[j] = __expf(s[j] - mx); l += pw[j]; }
  l += __shfl_xor(l, 1, 64);
  l += __shfl_xor(l, 2, 64);

  // pass 2: PV with packed f16 accumulation
  half2v acch[16];
  #pragma unroll
  for (int i = 0; i < 16; ++i) acch[i] = (half2v)(_Float16)0.0f;
  #pragma unroll
  for (int j = 0; j < NL; ++j) {
    int n = sl + 4 * j;
    if (n < K * K) {
      int kh = n / K, kw = n % K;
      int lidx = (rbase + kh) * H8 + (cbase + kw);
      const _Float16* vp = Vl + lidx * LSTR;
      _Float16 ph = (_Float16)pw[j];
      half2v pp = {ph, ph};
      #pragma unroll
      for (int u = 0; u < 4; ++u) {
        uint4 vv = *(const uint4*)(vp + u * 8);
        acch[4 * u + 0] += pp * __builtin_bit_cast(half2v, vv.x);
        acch[4 * u + 1] += pp * __builtin_bit_cast(half2v, vv.y);
        acch[4 * u + 2] += pp * __builtin_bit_cast(half2v, vv.z);
        acch[4 * u + 3] += pp * __builtin_bit_cast(half2v, vv.w);
      }
    }
  }
  // butterfly-sum accumulators over the 4 lanes
  #pragma unroll
  for (int st = 1; st <= 2; st <<= 1) {
    #pragma unroll
    for (int i = 0; i < 16; ++i) {
      unsigned int o = __shfl_xor(__builtin_bit_cast(unsigned int, acch[i]), st, 64);
      acch[i] += __builtin_bit_cast(half2v, o);
    }
  }

  if (valid) {
    float inv = 1.0f / l;
    _Float16 ih = (_Float16)inv;
    half2v iv = {ih, ih};
    // lane sl writes dims [8sl, 8sl+8) = pair-regs acch[4sl .. 4sl+3]
    unsigned int a[16];
    #pragma unroll
    for (int i = 0; i < 16; ++i) a[i] = __builtin_bit_cast(unsigned int, acch[i]);
    uint4 pk;
    unsigned int r0, r1, r2, r3;
    r0 = (sl < 2) ? ((sl == 0) ? a[0] : a[4]) : ((sl == 2) ? a[8] : a[12]);
    r1 = (sl < 2) ? ((sl == 0) ? a[1] : a[5]) : ((sl == 2) ? a[9] : a[13]);
    r2 = (sl < 2) ? ((sl == 0) ? a[2] : a[6]) : ((sl == 2) ? a[10] : a[14]);
    r3 = (sl < 2) ? ((sl == 0) ? a[3] : a[7]) : ((sl == 2) ? a[11] : a[15]);
    pk.x = __builtin_bit_cast(unsigned int, __builtin_bit_cast(half2v, r0) * iv);
    pk.y = __builtin_bit_cast(unsigned int, __builtin_bit_cast(half2v, r1) * iv);
    pk.z = __builtin_bit_cast(unsigned int, __builtin_bit_cast(half2v, r2) * iv);
    pk.w = __builtin_bit_cast(unsigned int, __builtin_bit_cast(half2v, r3) * iv);
    const int p = bb * 4096 + (gh + ci * DIL) * 64 + (gw + cj * DIL);
    *(uint4*)(yo + (size_t)p * 192 + branch * 64 + head * 32 + sl * 8) = pk;
  }
}

__global__ __launch_bounds__(256) void natten_all(
    const _Float16* __restrict__ qkv,
    const float* __restrict__ rpb0, const float* __restrict__ rpb1,
    const float* __restrict__ rpb2, _Float16* __restrict__ yo) {
  __shared__ __align__(16) unsigned short smem[18624];  // max: K=7 -> 37.2 KB
  const int gid = blockIdx.x;
  if (gid < 1296)       natten_branch<7, 3>(qkv, rpb2, yo, 2, gid, smem);
  else if (gid < 2320)  natten_branch<5, 2>(qkv, rpb1, yo, 1, gid - 1296, smem);
  else                  natten_branch<3, 1>(qkv, rpb0, yo, 0, gid - 2320, smem);
}

// ---------------- kernel 3: proj GEMM (C^T for coalesced NCHW f32 stores) ----------------
// Grid (512 px-tiles, 3 c-tiles): y staged in LDS; W fragments direct from global f16.
__global__ __launch_bounds__(256) void proj_gemm(
    const _Float16* __restrict__ y, const _Float16* __restrict__ wh,
    const float* __restrict__ bias, float* __restrict__ out) {
  __shared__ _Float16 Bl[64 * LDK];  // y tile (pixels x K)
  const int t = threadIdx.x;
  const int tp = blockIdx.x;       // 512 pixel tiles
  const int c0 = blockIdx.y * 64;  // out-channel tile

  const _Float16* ybp = y + (size_t)(tp * 64) * 192;
  #pragma unroll
  for (int j = 0; j < 6; ++j) {
    int idx = j * 256 + t;
    int m = idx / 24, k8 = (idx % 24) * 8;
    *(uint4*)&Bl[m * LDK + k8] = *(const uint4*)(ybp + m * 192 + k8);
  }
  __syncthreads();

  const int lane = t & 63, wid = t >> 6;
  const int wm = (wid >> 1) * 32, wn = (wid & 1) * 32;
  const int lr = lane & 15, kb = (lane >> 4) * 8;
  const int r0 = (lane >> 4) * 4;
  const int gp = tp * 64;
  const int bb = gp >> 12, hw0 = gp & 4095;
  float* op = out + (size_t)bb * 192 * 4096 + hw0;

  f32x4 acc[2][2];
  #pragma unroll
  for (int i = 0; i < 2; ++i)
    #pragma unroll
    for (int j = 0; j < 2; ++j)
      #pragma unroll
      for (int r = 0; r < 4; ++r) acc[i][j][r] = 0.0f;

  #pragma unroll
  for (int kk = 0; kk < 192; kk += 32) {
    half8 a0 = *(const half8*)(wh + (size_t)(c0 + wm + lr) * 192 + kk + kb);
    half8 a1 = *(const half8*)(wh + (size_t)(c0 + wm + 16 + lr) * 192 + kk + kb);
    half8 b0 = *(const half8*)&Bl[(wn + lr) * LDK + kk + kb];
    half8 b1 = *(const half8*)&Bl[(wn + 16 + lr) * LDK + kk + kb];
    acc[0][0] = __builtin_amdgcn_mfma_f32_16x16x32_f16(a0, b0, acc[0][0], 0, 0, 0);
    acc[0][1] = __builtin_amdgcn_mfma_f32_16x16x32_f16(a0, b1, acc[0][1], 0, 0, 0);
    acc[1][0] = __builtin_amdgcn_mfma_f32_16x16x32_f16(a1, b0, acc[1][0], 0, 0, 0);
    acc[1][1] = __builtin_amdgcn_mfma_f32_16x16x32_f16(a1, b1, acc[1][1], 0, 0, 0);
  }

  #pragma unroll
  for (int i = 0; i < 2; ++i)
    #pragma unroll
    for (int j = 0; j < 2; ++j) {
      int m = wn + j * 16 + lr;  // pixel (D col)
      #pragma unroll
      for (int r = 0; r < 4; ++r) {
        int c = c0 + wm + i * 16 + r0 + r;  // out channel (D row)
        op[(size_t)c * 4096 + m] = acc[i][j][r] + bias[c];
      }
    }
}

// ---------------- launch ----------------
extern "C" void kernel_launch(void* const* d_in, const int* in_sizes, int n_in,
                              void* d_out, int out_size, void* d_ws, size_t ws_size,
                              hipStream_t stream) {
  const float* x      = (const float*)d_in[0];
  const float* qkv_w  = (const float*)d_in[1];
  const float* qkv_b  = (const float*)d_in[2];
  const float* proj_w = (const float*)d_in[3];
  const float* proj_b = (const float*)d_in[4];
  const float* rpb0   = (const float*)d_in[5];
  const float* rpb1   = (const float*)d_in[6];
  const float* rpb2   = (const float*)d_in[7];

  // ws layout (ws ~256MB; we use ~50.7MB):
  //   qkv f16 [32768*576], yb f16 [32768*192], qwh f16 [110592], qbs f32 [576], pwh f16 [36864]
  _Float16* qkv = (_Float16*)d_ws;
  _Float16* yb  = qkv + (size_t)32768 * 576;
  _Float16* qwh = yb + (size_t)32768 * 192;
  float*    qbs = (float*)(qwh + 110592);
  _Float16* pwh = (_Float16*)(qbs + 576);
  float* out = (float*)d_out;

  prep_w<<<dim3(147), 256, 0, stream>>>(qkv_w, qkv_b, proj_w, qwh, qbs, pwh);
  qkv_gemm<<<dim3(512, 3), 256, 0, stream>>>(x, qwh, qbs, qkv);
  natten_all<<<dim3(3344), 256, 0, stream>>>(qkv, rpb0, rpb1, rpb2, yb);
  proj_gemm<<<dim3(512, 3), 256, 0, stream>>>(yb, pwh, proj_b, out);
}